// Round 16
// baseline (78.286 us; speedup 1.0000x reference)
//
#include <hip/hip_runtime.h>

#define NQ     50000
#define MS     50000
#define NH     32
#define NK     15
#define CIN    64
#define COUT   128
#define QT     32               // queries per tile; block processes 2 tiles
#define INV_EXT (1.0f/0.06f)

typedef unsigned int   uint32;
typedef unsigned short u16;
typedef _Float16 f16;
typedef _Float16 f16x8 __attribute__((ext_vector_type(8)));
typedef float    f32x4 __attribute__((ext_vector_type(4)));

#define WB_BYTES  (8*32*64*8*2)   // 262144
#define XPH_BYTES (MS*CIN*2)

#if __has_builtin(__builtin_amdgcn_sqrtf)
#define SQRTF __builtin_amdgcn_sqrtf
#else
#define SQRTF sqrtf
#endif

__device__ __forceinline__ uint32 permlo(uint32 A, uint32 B) {
#if __has_builtin(__builtin_amdgcn_perm)
    return __builtin_amdgcn_perm(A, B, 0x01000504u);
#else
    return (A & 0xffffu) | (B << 16);
#endif
}
__device__ __forceinline__ uint32 permhi(uint32 A, uint32 B) {
#if __has_builtin(__builtin_amdgcn_perm)
    return __builtin_amdgcn_perm(A, B, 0x03020706u);
#else
    return (A >> 16) | (B & 0xffff0000u);
#endif
}

__device__ __forceinline__ u16 f16bits(float f) {
    return __builtin_bit_cast(u16, (f16)f);
}

__device__ __forceinline__ uint32 pk2(float a, float b) {
#if __has_builtin(__builtin_amdgcn_cvt_pkrtz)
    return __builtin_bit_cast(uint32, __builtin_amdgcn_cvt_pkrtz(a, b));
#else
    return (uint32)f16bits(a) | ((uint32)f16bits(b) << 16);
#endif
}

// Reference swizzle: swA(o) = o ^ ((((o>>11)&7) ^ ((o>>7)&1)) << 4).  Folded forms verified R12.

// ---- merged pack ----
__global__ __launch_bounds__(256)
void pack_all(const float* __restrict__ x, u16* __restrict__ xph,
              const float* __restrict__ w, u16* __restrict__ wb) {
    const int bid = blockIdx.x;
    if (bid < 3125) {
        const int tid = bid * 256 + threadIdx.x;
        const int row = tid >> 4;
        const int lp  = tid & 15;
        const float v0 = x[row*CIN +  0 + lp];
        const float v1 = x[row*CIN + 16 + lp];
        const float v2 = x[row*CIN + 32 + lp];
        const float v3 = x[row*CIN + 48 + lp];
        uint2 d;
        d.x = pk2(v0, v1);
        d.y = pk2(v2, v3);
        *(uint2*)&xph[row*CIN + lp*4] = d;
    } else {
        const int u  = (bid - 3125) * 4 + (threadIdx.x >> 6);
        const int nt = u >> 5;
        const int ks = u & 31;
        const int l  = threadIdx.x & 63;
        u16 frag[8];
        #pragma unroll
        for (int e = 0; e < 8; ++e) {
            const int Kp = ks*32 + (l >> 4)*8 + e;
            const int c  = Kp >> 4;
            const int k  = Kp & 15;
            const float val = (k < NK) ? w[(k*CIN + c)*COUT + nt*16 + (l & 15)] : 0.0f;
            frag[e] = f16bits(val);
        }
        *(f16x8*)&wb[((nt*32 + ks)*64 + l)*8] = *(f16x8*)frag;
    }
}

struct BRes { uint2 d[8]; };    // 2 queries x 4 ct, packed fp16 pairs

// ---- fused KPConv: 2-tile pipeline, C(T0) overlapped with B-compute(T1) ----
__global__ __launch_bounds__(512, 4)
void kpconv_fused(const float* __restrict__ q_pts,
                  const float* __restrict__ s_pts,
                  const u16*  __restrict__ xph,
                  const u16*  __restrict__ wb,
                  const float* __restrict__ kp,
                  const int*   __restrict__ nind,
                  float* __restrict__ out)
{
    __shared__ u16 fpkAT[QT*1024];    // 65536 B, swizzled [q][c][k16]
    __shared__ u16 nbh[2][QT*96];     // 12288 B: f16 coords [tile][q*96 + coord*32 + j]
                                      // total 77824 B -> 2 blocks/CU

    const int t   = threadIdx.x;
    const int q00 = blockIdx.x * (2*QT);       // tile0 global base
    const int q01 = q00 + QT;                  // tile1 global base

    const int l  = t & 63, wv = t >> 6;
    const int lc = l & 15, lg = l >> 4;
    const int kc = (lc < NK) ? lc : (NK - 1);
    const float kx = kp[kc*3+0], ky = kp[kc*3+1], kz = kp[kc*3+2];
    const uint32 lcxor = (uint32)(lc & 4) << 2;

    // ---------- stage: centered coords as f16 into nbh[tl] ----------
    auto STAGE = [&](int tl, int qb) {
        #pragma unroll
        for (int p = t; p < QT*NH; p += 512) {
            const int q = p >> 5, j = p & 31;
            const int qg = qb + q;
            const int qc = (qg < NQ) ? qg : (NQ - 1);
            const int ind = nind[qc*NH + j];
            const bool valid = (ind < MS);
            float sx, sy, sz;
            if (valid) { sx = s_pts[ind*3+0]; sy = s_pts[ind*3+1]; sz = s_pts[ind*3+2]; }
            else       { sx = 1e6f; sy = 1e6f; sz = 1e6f; }   // f16 -> +inf -> h = 0
            u16* nq = &nbh[tl][q*96];
            nq[0*32 + j] = f16bits(sx - q_pts[qc*3+0]);
            nq[1*32 + j] = f16bits(sy - q_pts[qc*3+1]);
            nq[2*32 + j] = f16bits(sz - q_pts[qc*3+2]);
        }
    };

    // ---------- B-compute for query pair (qloc, qloc+1) of tile tl; results held ----------
    auto B_PAIR = [&](int tl, int qb, int qloc) -> BRes {
        BRes res;
        #pragma unroll
        for (int s = 0; s < 2; ++s) {
            const int q  = qloc + s;
            const int qg = qb + q;
            const int qc = (qg < NQ) ? qg : (NQ - 1);
            // neighbor indices straight from global (L2-hot, broadcast across 16 lanes)
            const int4 i0 = *(const int4*)(nind + qc*NH + lg*8);
            const int4 i1 = *(const int4*)(nind + qc*NH + lg*8 + 4);
            uint2 v[8];
            {
                const int rr[8] = { i0.x, i0.y, i0.z, i0.w, i1.x, i1.y, i1.z, i1.w };
                #pragma unroll
                for (int e = 0; e < 8; ++e) {
                    const int ic = (rr[e] < MS) ? rr[e] : 0;   // shadow: gather row 0, h=0 kills it
                    v[e] = *(const uint2*)(xph + ic*CIN + lc*4);
                }
            }
            // h from f16 nb (3 x ds_read_b128, broadcast in 16-lane groups)
            const u16* nq = &nbh[tl][q*96];
            const f16x8 xs = *(const f16x8*)&nq[0*32 + lg*8];
            const f16x8 ys = *(const f16x8*)&nq[1*32 + lg*8];
            const f16x8 zs = *(const f16x8*)&nq[2*32 + lg*8];
            float hh[8];
            #pragma unroll
            for (int e = 0; e < 8; ++e) {
                const float dx = (float)xs[e] - kx;
                const float dy = (float)ys[e] - ky;
                const float dz = (float)zs[e] - kz;
                float h = 1.0f - SQRTF(dx*dx + dy*dy + dz*dz) * INV_EXT;
                hh[e] = (h > 0.0f) ? h : 0.0f;
            }
            uint32 ab[4];
            ab[0] = pk2(hh[0], hh[1]); ab[1] = pk2(hh[2], hh[3]);
            ab[2] = pk2(hh[4], hh[5]); ab[3] = pk2(hh[6], hh[7]);
            const f16x8 a = __builtin_bit_cast(f16x8, *(uint4*)ab);
            f32x4 acc0 = {0,0,0,0}, acc1 = {0,0,0,0}, acc2 = {0,0,0,0}, acc3 = {0,0,0,0};
            #pragma unroll
            for (int ct = 0; ct < 4; ++ct) {
                const uint32 A0 = (ct & 2) ? v[0].y : v[0].x, B0 = (ct & 2) ? v[1].y : v[1].x;
                const uint32 A1 = (ct & 2) ? v[2].y : v[2].x, B1 = (ct & 2) ? v[3].y : v[3].x;
                const uint32 A2 = (ct & 2) ? v[4].y : v[4].x, B2 = (ct & 2) ? v[5].y : v[5].x;
                const uint32 A3 = (ct & 2) ? v[6].y : v[6].x, B3 = (ct & 2) ? v[7].y : v[7].x;
                uint4 bd;
                if (ct & 1) {
                    bd.x = permhi(A0, B0); bd.y = permhi(A1, B1);
                    bd.z = permhi(A2, B2); bd.w = permhi(A3, B3);
                } else {
                    bd.x = permlo(A0, B0); bd.y = permlo(A1, B1);
                    bd.z = permlo(A2, B2); bd.w = permlo(A3, B3);
                }
                const f16x8 b = __builtin_bit_cast(f16x8, bd);
                if      (ct == 0) acc0 = __builtin_amdgcn_mfma_f32_16x16x32_f16(a, b, acc0, 0,0,0);
                else if (ct == 1) acc1 = __builtin_amdgcn_mfma_f32_16x16x32_f16(a, b, acc1, 0,0,0);
                else if (ct == 2) acc2 = __builtin_amdgcn_mfma_f32_16x16x32_f16(a, b, acc2, 0,0,0);
                else              acc3 = __builtin_amdgcn_mfma_f32_16x16x32_f16(a, b, acc3, 0,0,0);
            }
            #pragma unroll
            for (int ct = 0; ct < 4; ++ct) {
                const f32x4 av = (ct==0)?acc0:(ct==1)?acc1:(ct==2)?acc2:acc3;
                uint2 dv;
                dv.x = pk2(av[0], av[1]);
                dv.y = pk2(av[2], av[3]);
                res.d[s*4 + ct] = dv;
            }
        }
        return res;
    };

    // ---------- write held results into swizzled fpkAT ----------
    auto B_WRITE = [&](int qloc, const BRes& res) {
        #pragma unroll
        for (int s = 0; s < 2; ++s) {
            const int q = qloc + s;
            const uint32 wbase = ((uint32)(q*2048 + lc*32 + lg*8))
                                 ^ (((uint32)(q & 7)) << 4) ^ lcxor;
            char* wp = (char*)fpkAT + wbase;
            #pragma unroll
            for (int ct = 0; ct < 4; ++ct)
                *(uint2*)(wp + ct*512) = res.d[s*4 + ct];
        }
    };

    // ---------- Phase C for one tile (base qb): wave = nt, both 16q A-tiles ----------
    auto CPHASE = [&](int qb) {
        const int nt = wv;
        const u16* bp = wb + (nt*32)*512 + l*8;
        f32x4 acc0 = {0.f,0.f,0.f,0.f};
        f32x4 acc1 = {0.f,0.f,0.f,0.f};
        const uint32 b0 = ((uint32)(lc*2048 + lg*16)) ^ (((uint32)(lc & 7)) << 4);
        const char* base = (const char*)fpkAT;
        const char* p0 = base + (b0);
        const char* p1 = base + (b0 ^ 64u);
        const char* p2 = base + (b0 ^ 144u);
        const char* p3 = base + (b0 ^ 208u);
        #pragma unroll
        for (int ks = 0; ks < 32; ++ks) {
            const char* sel = ((ks & 3) == 0) ? p0 : ((ks & 3) == 1) ? p1
                            : ((ks & 3) == 2) ? p2 : p3;
            const int off = (ks >> 2) * 256;
            const f16x8 a0 = *(const f16x8*)(sel + off);
            const f16x8 a1 = *(const f16x8*)(sel + off + 32768);
            const uint4 bd = *(const uint4*)(bp + ks*512);
            const f16x8 b = __builtin_bit_cast(f16x8, bd);
            acc0 = __builtin_amdgcn_mfma_f32_16x16x32_f16(a0, b, acc0, 0, 0, 0);
            acc1 = __builtin_amdgcn_mfma_f32_16x16x32_f16(a1, b, acc1, 0, 0, 0);
        }
        const int rbase = lg * 4;
        #pragma unroll
        for (int r = 0; r < 4; ++r) {
            const int row0 = qb + rbase + r;
            const int row1 = row0 + 16;
            if (row0 < NQ) out[row0*COUT + nt*16 + lc] = acc0[r];
            if (row1 < NQ) out[row1*COUT + nt*16 + lc] = acc1[r];
        }
    };

    // ================= pipeline =================
    STAGE(0, q00);
    __syncthreads();                                   // bar1: nb(T0) ready

    {   // B(T0) immediate-write, plus stage(T1) in the same phase
        const BRes r0 = B_PAIR(0, q00, wv*4 + 0);
        B_WRITE(wv*4 + 0, r0);
        const BRes r1 = B_PAIR(0, q00, wv*4 + 2);
        B_WRITE(wv*4 + 2, r1);
        STAGE(1, q01);                                 // writes nbh[1] (disjoint from nbh[0])
    }
    __syncthreads();                                   // bar2: fpkAT(T0) + nb(T1) ready

    // ---- overlapped region: C(T0) then B-compute(T1); no barrier between ----
    CPHASE(q00);
    const BRes h0 = B_PAIR(1, q01, wv*4 + 0);          // held in registers
    const BRes h1 = B_PAIR(1, q01, wv*4 + 2);
    __syncthreads();                                   // bar3: all C(T0) fpkAT reads done

    B_WRITE(wv*4 + 0, h0);
    B_WRITE(wv*4 + 2, h1);
    __syncthreads();                                   // bar4: fpkAT(T1) ready

    CPHASE(q01);
}

extern "C" void kernel_launch(void* const* d_in, const int* in_sizes, int n_in,
                              void* d_out, int out_size, void* d_ws, size_t ws_size,
                              hipStream_t stream) {
    const float* q_pts = (const float*)d_in[0];
    const float* s_pts = (const float*)d_in[1];
    const float* x     = (const float*)d_in[2];
    const float* wts   = (const float*)d_in[3];
    const float* kp    = (const float*)d_in[4];
    const int*   nind  = (const int*)d_in[5];
    float* out = (float*)d_out;

    u16* wbp = (u16*)d_ws;
    u16* xph = (u16*)((char*)d_ws + WB_BYTES);

    hipLaunchKernelGGL(pack_all, dim3(3125 + 64), dim3(256), 0, stream, x, xph, wts, wbp);
    hipLaunchKernelGGL(kpconv_fused, dim3((NQ + 2*QT - 1) / (2*QT)), dim3(512), 0, stream,
                       q_pts, s_pts, xph, wbp, kp, nind, out);
}

// Round 17
// 60.167 us; speedup vs baseline: 1.3011x; 1.3011x over previous
//
#include <hip/hip_runtime.h>

#define NQ     50000
#define MS     50000
#define NH     32
#define NK     15
#define CIN    64
#define COUT   128
#define QT     32
#define INV_EXT (1.0f/0.06f)

typedef unsigned int   uint32;
typedef unsigned short u16;
typedef _Float16 f16;
typedef _Float16 f16x8 __attribute__((ext_vector_type(8)));
typedef float    f32x4 __attribute__((ext_vector_type(4)));

#define WB_BYTES  (8*32*64*8*2)   // 262144
#define XPH_BYTES (MS*CIN*2)

#if __has_builtin(__builtin_amdgcn_sqrtf)
#define SQRTF __builtin_amdgcn_sqrtf
#else
#define SQRTF sqrtf
#endif

__device__ __forceinline__ uint32 permlo(uint32 A, uint32 B) {
#if __has_builtin(__builtin_amdgcn_perm)
    return __builtin_amdgcn_perm(A, B, 0x01000504u);
#else
    return (A & 0xffffu) | (B << 16);
#endif
}
__device__ __forceinline__ uint32 permhi(uint32 A, uint32 B) {
#if __has_builtin(__builtin_amdgcn_perm)
    return __builtin_amdgcn_perm(A, B, 0x03020706u);
#else
    return (A >> 16) | (B & 0xffff0000u);
#endif
}

__device__ __forceinline__ u16 f16bits(float f) {
    return __builtin_bit_cast(u16, (f16)f);
}

__device__ __forceinline__ uint32 pk2(float a, float b) {
#if __has_builtin(__builtin_amdgcn_cvt_pkrtz)
    return __builtin_bit_cast(uint32, __builtin_amdgcn_cvt_pkrtz(a, b));
#else
    return (uint32)f16bits(a) | ((uint32)f16bits(b) << 16);
#endif
}

// Reference swizzle: swA(o) = o ^ ((((o>>11)&7) ^ ((o>>7)&1)) << 4).
// Folded forms (verified R12):
//  B write: wbase = (q*2048+lc*32+lg*8) ^ ((q&7)<<4) ^ ((lc&4)<<2); +ct*512 carry-free
//  C read : p[ks&3] = (col*2048+kg*16) ^ ((col&7)<<4) ^ {0,64,144,208}[ks&3];
//           addr = p[ks&3] + (ks>>2)*256 (+32768 for A-tile 1), carry-free

// ---- merged pack ----
__global__ __launch_bounds__(256)
void pack_all(const float* __restrict__ x, u16* __restrict__ xph,
              const float* __restrict__ w, u16* __restrict__ wb) {
    const int bid = blockIdx.x;
    if (bid < 3125) {
        const int tid = bid * 256 + threadIdx.x;
        const int row = tid >> 4;
        const int lp  = tid & 15;
        const float v0 = x[row*CIN +  0 + lp];
        const float v1 = x[row*CIN + 16 + lp];
        const float v2 = x[row*CIN + 32 + lp];
        const float v3 = x[row*CIN + 48 + lp];
        uint2 d;
        d.x = pk2(v0, v1);
        d.y = pk2(v2, v3);
        *(uint2*)&xph[row*CIN + lp*4] = d;
    } else {
        const int u  = (bid - 3125) * 4 + (threadIdx.x >> 6);
        const int nt = u >> 5;
        const int ks = u & 31;
        const int l  = threadIdx.x & 63;
        u16 frag[8];
        #pragma unroll
        for (int e = 0; e < 8; ++e) {
            const int Kp = ks*32 + (l >> 4)*8 + e;
            const int c  = Kp >> 4;
            const int k  = Kp & 15;
            const float val = (k < NK) ? w[(k*CIN + c)*COUT + nt*16 + (l & 15)] : 0.0f;
            frag[e] = f16bits(val);
        }
        *(f16x8*)&wb[((nt*32 + ks)*64 + l)*8] = *(f16x8*)frag;
    }
}

// ---- fused KPConv: R12 mapping + double-buffered Phase C B-loads (R14, best measured) ----
__global__ __launch_bounds__(512, 4)
void kpconv_fused(const float* __restrict__ q_pts,
                  const float* __restrict__ s_pts,
                  const u16*  __restrict__ xph,
                  const u16*  __restrict__ wb,
                  const float* __restrict__ kp,
                  const int*   __restrict__ nind,
                  float* __restrict__ out)
{
    __shared__ u16   fpkAT[QT*1024];   // 65536 B
    __shared__ float nb[QT*100];       // 12800 B
    __shared__ u16   inds[QT*NH];      // 2048 B -> total 80384 B, 2 blocks/CU

    const int t  = threadIdx.x;
    const int q0 = blockIdx.x * QT;

    // ---------------- stage ----------------
    #pragma unroll
    for (int p = t; p < QT*NH; p += 512) {
        const int q = p >> 5, j = p & 31;
        const int qg = q0 + q;
        const int qc = (qg < NQ) ? qg : (NQ - 1);
        const int ind = nind[qc*NH + j];
        const bool valid = (ind < MS);
        inds[p] = (u16)(valid ? ind : 0);
        float sx, sy, sz;
        if (valid) { sx = s_pts[ind*3+0]; sy = s_pts[ind*3+1]; sz = s_pts[ind*3+2]; }
        else       { sx = 1e6f; sy = 1e6f; sz = 1e6f; }
        nb[q*100 + j*3 + 0] = sx - q_pts[qc*3+0];
        nb[q*100 + j*3 + 1] = sy - q_pts[qc*3+1];
        nb[q*100 + j*3 + 2] = sz - q_pts[qc*3+2];
    }
    __syncthreads();

    // ---------------- Phase B ----------------
    {
        const int l  = t & 63, wv = t >> 6;
        const int lc = l & 15, lg = l >> 4;
        const int kc = (lc < NK) ? lc : (NK - 1);
        const float kx = kp[kc*3+0], ky = kp[kc*3+1], kz = kp[kc*3+2];
        const uint32 lcxor = (uint32)(lc & 4) << 2;

        uint2 v[4][8];
        #pragma unroll
        for (int qi = 0; qi < 4; ++qi) {
            const int q = wv*4 + qi;
            const uint4 iv = *(const uint4*)&inds[q*NH + lg*8];
            uint32 r[8];
            r[0] = iv.x & 0xffffu; r[1] = iv.x >> 16;
            r[2] = iv.y & 0xffffu; r[3] = iv.y >> 16;
            r[4] = iv.z & 0xffffu; r[5] = iv.z >> 16;
            r[6] = iv.w & 0xffffu; r[7] = iv.w >> 16;
            #pragma unroll
            for (int e = 0; e < 8; ++e)
                v[qi][e] = *(const uint2*)(xph + r[e]*CIN + lc*4);
        }
        __builtin_amdgcn_sched_barrier(0);

        #pragma unroll
        for (int qi = 0; qi < 4; ++qi) {
            const int q = wv*4 + qi;
            const float* nbq = &nb[q*100 + lg*24];
            const float4 r0 = *(const float4*)(nbq +  0);
            const float4 r1 = *(const float4*)(nbq +  4);
            const float4 r2 = *(const float4*)(nbq +  8);
            const float4 r3 = *(const float4*)(nbq + 12);
            const float4 r4 = *(const float4*)(nbq + 16);
            const float4 r5 = *(const float4*)(nbq + 20);
            float jx[8], jy[8], jz[8];
            jx[0]=r0.x; jy[0]=r0.y; jz[0]=r0.z;
            jx[1]=r0.w; jy[1]=r1.x; jz[1]=r1.y;
            jx[2]=r1.z; jy[2]=r1.w; jz[2]=r2.x;
            jx[3]=r2.y; jy[3]=r2.z; jz[3]=r2.w;
            jx[4]=r3.x; jy[4]=r3.y; jz[4]=r3.z;
            jx[5]=r3.w; jy[5]=r4.x; jz[5]=r4.y;
            jx[6]=r4.z; jy[6]=r4.w; jz[6]=r5.x;
            jx[7]=r5.y; jy[7]=r5.z; jz[7]=r5.w;
            float hh[8];
            #pragma unroll
            for (int e = 0; e < 8; ++e) {
                const float dx = jx[e] - kx;
                const float dy = jy[e] - ky;
                const float dz = jz[e] - kz;
                float h = 1.0f - SQRTF(dx*dx + dy*dy + dz*dz) * INV_EXT;
                hh[e] = (h > 0.0f) ? h : 0.0f;
            }
            uint32 ab[4];
            ab[0] = pk2(hh[0], hh[1]); ab[1] = pk2(hh[2], hh[3]);
            ab[2] = pk2(hh[4], hh[5]); ab[3] = pk2(hh[6], hh[7]);
            const f16x8 a = __builtin_bit_cast(f16x8, *(uint4*)ab);
            f32x4 acc0 = {0,0,0,0}, acc1 = {0,0,0,0}, acc2 = {0,0,0,0}, acc3 = {0,0,0,0};
            #pragma unroll
            for (int ct = 0; ct < 4; ++ct) {
                const uint32 A0 = (ct & 2) ? v[qi][0].y : v[qi][0].x, B0 = (ct & 2) ? v[qi][1].y : v[qi][1].x;
                const uint32 A1 = (ct & 2) ? v[qi][2].y : v[qi][2].x, B1 = (ct & 2) ? v[qi][3].y : v[qi][3].x;
                const uint32 A2 = (ct & 2) ? v[qi][4].y : v[qi][4].x, B2 = (ct & 2) ? v[qi][5].y : v[qi][5].x;
                const uint32 A3 = (ct & 2) ? v[qi][6].y : v[qi][6].x, B3 = (ct & 2) ? v[qi][7].y : v[qi][7].x;
                uint4 bd;
                if (ct & 1) {
                    bd.x = permhi(A0, B0); bd.y = permhi(A1, B1);
                    bd.z = permhi(A2, B2); bd.w = permhi(A3, B3);
                } else {
                    bd.x = permlo(A0, B0); bd.y = permlo(A1, B1);
                    bd.z = permlo(A2, B2); bd.w = permlo(A3, B3);
                }
                const f16x8 b = __builtin_bit_cast(f16x8, bd);
                if      (ct == 0) acc0 = __builtin_amdgcn_mfma_f32_16x16x32_f16(a, b, acc0, 0,0,0);
                else if (ct == 1) acc1 = __builtin_amdgcn_mfma_f32_16x16x32_f16(a, b, acc1, 0,0,0);
                else if (ct == 2) acc2 = __builtin_amdgcn_mfma_f32_16x16x32_f16(a, b, acc2, 0,0,0);
                else              acc3 = __builtin_amdgcn_mfma_f32_16x16x32_f16(a, b, acc3, 0,0,0);
            }
            {
                const uint32 wbase = ((uint32)(q*2048 + lc*32 + lg*8))
                                     ^ (((uint32)(q & 7)) << 4) ^ lcxor;
                char* wp = (char*)fpkAT + wbase;
                #pragma unroll
                for (int ct = 0; ct < 4; ++ct) {
                    const f32x4 av = (ct==0)?acc0:(ct==1)?acc1:(ct==2)?acc2:acc3;
                    uint2 dv;
                    dv.x = pk2(av[0], av[1]);
                    dv.y = pk2(av[2], av[3]);
                    *(uint2*)(wp + ct*512) = dv;
                }
            }
        }
    }

    // ---- Phase C group-0 B-prefetch (independent of fpkAT) ----
    const int l  = t & 63;
    const int nt = t >> 6;
    const u16* bp = wb + (nt*32)*512 + l*8;
    uint4 bufA[8], bufB[8];
    #pragma unroll
    for (int e = 0; e < 8; ++e) bufA[e] = *(const uint4*)(bp + e*512);

    __syncthreads();

    // ---------------- Phase C ----------------
    {
        const int col = l & 15;
        const int kg  = l >> 4;
        f32x4 acc0 = {0.f,0.f,0.f,0.f};
        f32x4 acc1 = {0.f,0.f,0.f,0.f};
        const uint32 b0 = ((uint32)(col*2048 + kg*16)) ^ (((uint32)(col & 7)) << 4);
        const char* base = (const char*)fpkAT;
        const char* p0 = base + (b0);
        const char* p1 = base + (b0 ^ 64u);
        const char* p2 = base + (b0 ^ 144u);
        const char* p3 = base + (b0 ^ 208u);

#define PROC(G, BUF)                                                              \
        _Pragma("unroll")                                                         \
        for (int e = 0; e < 8; ++e) {                                             \
            const int ks = (G)*8 + e;                                             \
            const char* sel = ((ks & 3) == 0) ? p0 : ((ks & 3) == 1) ? p1         \
                            : ((ks & 3) == 2) ? p2 : p3;                          \
            const int off = (ks >> 2) * 256;                                      \
            const f16x8 a0 = *(const f16x8*)(sel + off);                          \
            const f16x8 a1 = *(const f16x8*)(sel + off + 32768);                  \
            const f16x8 b  = __builtin_bit_cast(f16x8, BUF[e]);                   \
            acc0 = __builtin_amdgcn_mfma_f32_16x16x32_f16(a0, b, acc0, 0, 0, 0);  \
            acc1 = __builtin_amdgcn_mfma_f32_16x16x32_f16(a1, b, acc1, 0, 0, 0);  \
        }

        #pragma unroll
        for (int e = 0; e < 8; ++e) bufB[e] = *(const uint4*)(bp + (8 + e)*512);
        __builtin_amdgcn_sched_barrier(0);
        PROC(0, bufA)
        #pragma unroll
        for (int e = 0; e < 8; ++e) bufA[e] = *(const uint4*)(bp + (16 + e)*512);
        __builtin_amdgcn_sched_barrier(0);
        PROC(1, bufB)
        #pragma unroll
        for (int e = 0; e < 8; ++e) bufB[e] = *(const uint4*)(bp + (24 + e)*512);
        __builtin_amdgcn_sched_barrier(0);
        PROC(2, bufA)
        PROC(3, bufB)
#undef PROC

        const int rbase = kg * 4;
        #pragma unroll
        for (int r = 0; r < 4; ++r) {
            const int row0 = q0 + rbase + r;
            const int row1 = row0 + 16;
            if (row0 < NQ) out[row0*COUT + nt*16 + col] = acc0[r];
            if (row1 < NQ) out[row1*COUT + nt*16 + col] = acc1[r];
        }
    }
}

extern "C" void kernel_launch(void* const* d_in, const int* in_sizes, int n_in,
                              void* d_out, int out_size, void* d_ws, size_t ws_size,
                              hipStream_t stream) {
    const float* q_pts = (const float*)d_in[0];
    const float* s_pts = (const float*)d_in[1];
    const float* x     = (const float*)d_in[2];
    const float* wts   = (const float*)d_in[3];
    const float* kp    = (const float*)d_in[4];
    const int*   nind  = (const int*)d_in[5];
    float* out = (float*)d_out;

    u16* wbp = (u16*)d_ws;
    u16* xph = (u16*)((char*)d_ws + WB_BYTES);

    hipLaunchKernelGGL(pack_all, dim3(3125 + 64), dim3(256), 0, stream, x, xph, wts, wbp);
    hipLaunchKernelGGL(kpconv_fused, dim3((NQ + QT - 1) / QT), dim3(512), 0, stream,
                       q_pts, s_pts, xph, wbp, kp, nind, out);
}